// Round 6
// baseline (35.754 us; speedup 1.0000x reference)
//
#include <hip/hip_runtime.h>
#include <math.h>

#define HH 64
#define WW 64
#define CC 256
#define NHEAD 8
#define HD 32
#define KW 7
#define NPIX (HH * WW)

// natten tile geometry: 2x8 pixels, halo 8x14
#define HALO_H 8
#define HALO_W 14
#define NRH (HALO_H * HALO_W)  // 112
#define KROW 40                // K/V LDS row stride in ushorts (80 B)
#define PST 51

typedef short short8v __attribute__((ext_vector_type(8)));
typedef float float4v __attribute__((ext_vector_type(4)));

__device__ __forceinline__ ushort f2bf(float f) {
  union { float f; unsigned u; } c;
  c.f = f;
  unsigned u = c.u;
  return (ushort)((u + 0x7FFFu + ((u >> 16) & 1u)) >> 16);
}
__device__ __forceinline__ unsigned pk2(float lo, float hi) {
  return (unsigned)f2bf(lo) | ((unsigned)f2bf(hi) << 16);
}
__device__ __forceinline__ float bflo(unsigned u) {
  union { unsigned i; float f; } c;
  c.i = u << 16;
  return c.f;
}
__device__ __forceinline__ float bfhi(unsigned u) {
  union { unsigned i; float f; } c;
  c.i = u & 0xFFFF0000u;
  return c.f;
}

// ---- bf16 MFMA GEMM with fused f32->bf16 conversion in reg-staging ----------
// C[M,N] = A[M,256] @ B[N,256]^T + bias. 64x64 tile, 4 waves x 32x32.
// K in 4x64 chunks, double-buffered LDS (32KB -> 5 blocks/CU), loads issued
// 2 chunks ahead, ds_write 1 chunk ahead, one barrier per chunk.
// ABF: A is bf16 (ushort) else f32 (converted in staging). B always f32.
template <int N, bool ABF, bool OB>
__global__ __launch_bounds__(256) void gemm4(
    const void* __restrict__ Ap, const float* __restrict__ Bw,
    const float* __restrict__ bias, void* __restrict__ Cd) {
  __shared__ ushort As[2][4096];
  __shared__ ushort Bs[2][4096];
  const int t = threadIdx.x;
  const int lane = t & 63;
  const int wave = t >> 6;
  const int bm = blockIdx.x * 64;
  const int bn = blockIdx.y * 64;

  const int r = t >> 2;     // staged row 0..63
  const int q = t & 3;      // k-quarter (16 elems)
  const int lin = r * 128 + q * 32;      // LDS byte offset (row stride 128B)
  const int sw  = (r & 7) << 4;          // XOR swizzle

  const float*  Aw = (const float*)Ap;
  const ushort* Ab = (const ushort*)Ap;

  float fA[2][16];
  float fB[2][16];
  unsigned wAb[2][8];

#define LOADA(c, s)                                                            \
  {                                                                            \
    if (ABF) {                                                                 \
      const ushort* p_ = Ab + (size_t)(bm + r) * 256 + (c) * 64 + q * 16;      \
      *(uint4*)&wAb[s][0] = *(const uint4*)p_;                                 \
      *(uint4*)&wAb[s][4] = *(const uint4*)(p_ + 8);                           \
    } else {                                                                   \
      const float* p_ = Aw + (size_t)(bm + r) * 256 + (c) * 64 + q * 16;       \
      *(float4*)&fA[s][0]  = *(const float4*)(p_);                             \
      *(float4*)&fA[s][4]  = *(const float4*)(p_ + 4);                         \
      *(float4*)&fA[s][8]  = *(const float4*)(p_ + 8);                         \
      *(float4*)&fA[s][12] = *(const float4*)(p_ + 12);                        \
    }                                                                          \
  }

#define LOADB(c, s)                                                            \
  {                                                                            \
    const float* p_ = Bw + (size_t)(bn + r) * 256 + (c) * 64 + q * 16;         \
    *(float4*)&fB[s][0]  = *(const float4*)(p_);                               \
    *(float4*)&fB[s][4]  = *(const float4*)(p_ + 4);                           \
    *(float4*)&fB[s][8]  = *(const float4*)(p_ + 8);                           \
    *(float4*)&fB[s][12] = *(const float4*)(p_ + 12);                          \
  }

#define WRITEC(b, s)                                                           \
  {                                                                            \
    unsigned wa[8], wb[8];                                                     \
    if (ABF) {                                                                 \
      _Pragma("unroll") for (int z_ = 0; z_ < 8; ++z_) wa[z_] = wAb[s][z_];    \
    } else {                                                                   \
      _Pragma("unroll") for (int z_ = 0; z_ < 8; ++z_)                         \
          wa[z_] = pk2(fA[s][2 * z_], fA[s][2 * z_ + 1]);                      \
    }                                                                          \
    _Pragma("unroll") for (int z_ = 0; z_ < 8; ++z_)                           \
        wb[z_] = pk2(fB[s][2 * z_], fB[s][2 * z_ + 1]);                        \
    char* ab_ = (char*)As[b];                                                  \
    char* bb_ = (char*)Bs[b];                                                  \
    *(uint4*)(ab_ + (lin ^ sw))        = *(uint4*)&wa[0];                      \
    *(uint4*)(ab_ + ((lin + 16) ^ sw)) = *(uint4*)&wa[4];                      \
    *(uint4*)(bb_ + (lin ^ sw))        = *(uint4*)&wb[0];                      \
    *(uint4*)(bb_ + ((lin + 16) ^ sw)) = *(uint4*)&wb[4];                      \
  }

  const int wr = (wave >> 1) * 32;
  const int wc = (wave & 1) * 32;
  const int lrow = lane & 15;
  const int lkb = (lane >> 4) * 16;

  float4v acc[2][2] = {{{0.f, 0.f, 0.f, 0.f}, {0.f, 0.f, 0.f, 0.f}},
                       {{0.f, 0.f, 0.f, 0.f}, {0.f, 0.f, 0.f, 0.f}}};

  LOADA(0, 0); LOADB(0, 0);
  WRITEC(0, 0);
  LOADA(1, 1); LOADB(1, 1);
  __syncthreads();

#pragma unroll
  for (int c = 0; c < 4; ++c) {
    if (c < 3) WRITEC((c + 1) & 1, (c + 1) & 1);
    if (c < 2) { LOADA(c + 2, c & 1); LOADB(c + 2, c & 1); }
    const char* Al = (const char*)As[c & 1];
    const char* Bl = (const char*)Bs[c & 1];
#pragma unroll
    for (int ks = 0; ks < 2; ++ks) {
      const int kb = ks * 64 + lkb;
      const int ra0 = (wr + lrow) * 128 + kb;
      const int ra1 = (wr + 16 + lrow) * 128 + kb;
      const int rb0 = (wc + lrow) * 128 + kb;
      const int rb1 = (wc + 16 + lrow) * 128 + kb;
      const short8v a0 = *(const short8v*)(Al + (ra0 ^ (((wr + lrow) & 7) << 4)));
      const short8v a1 = *(const short8v*)(Al + (ra1 ^ (((wr + 16 + lrow) & 7) << 4)));
      const short8v b0 = *(const short8v*)(Bl + (rb0 ^ (((wc + lrow) & 7) << 4)));
      const short8v b1 = *(const short8v*)(Bl + (rb1 ^ (((wc + 16 + lrow) & 7) << 4)));
      acc[0][0] = __builtin_amdgcn_mfma_f32_16x16x32_bf16(a0, b0, acc[0][0], 0, 0, 0);
      acc[0][1] = __builtin_amdgcn_mfma_f32_16x16x32_bf16(a0, b1, acc[0][1], 0, 0, 0);
      acc[1][0] = __builtin_amdgcn_mfma_f32_16x16x32_bf16(a1, b0, acc[1][0], 0, 0, 0);
      acc[1][1] = __builtin_amdgcn_mfma_f32_16x16x32_bf16(a1, b1, acc[1][1], 0, 0, 0);
    }
    if (c < 3) __syncthreads();
  }
#undef LOADA
#undef LOADB
#undef WRITEC

#pragma unroll
  for (int bi = 0; bi < 2; ++bi) {
#pragma unroll
    for (int bj = 0; bj < 2; ++bj) {
      const int n = bn + wc + bj * 16 + lrow;
      const float bv = bias[n];
      const int m0 = bm + wr + bi * 16 + (lane >> 4) * 4;
      if (OB) {
        ushort* C = (ushort*)Cd;
#pragma unroll
        for (int rr = 0; rr < 4; ++rr)
          C[(size_t)(m0 + rr) * N + n] = f2bf(acc[bi][bj][rr] + bv);
      } else {
        float* C = (float*)Cd;
#pragma unroll
        for (int rr = 0; rr < 4; ++rr)
          C[(size_t)(m0 + rr) * N + n] = acc[bi][bj][rr] + bv;
      }
    }
  }
}

// ---------------- natten5: 2x8 tiles, 16 lanes/pixel, 2048 blocks ------------
__global__ __launch_bounds__(256) void natten5(
    const ushort* __restrict__ qkv, const float* __restrict__ rpb,
    ushort* __restrict__ aout) {
  __shared__ ushort Ks[NRH * KROW];
  __shared__ ushort Vs[NRH * KROW];
  __shared__ float Ps[16][PST];
  __shared__ float Rs[169];

  const int head = blockIdx.y;
  const int tile = blockIdx.x;
  const int i0 = (tile >> 3) * 2, j0 = (tile & 7) * 8;
  const int hs = min(max(i0 - 3, 0), HH - HALO_H);
  const int ws = min(max(j0 - 3, 0), WW - HALO_W);
  const int t = threadIdx.x;

  if (t < 169) Rs[t] = rpb[head * 169 + t];

  // stage K,V halo rows (bf16): 224 row-tasks, 4 lanes x 16B per row
  {
    const int lane4 = t & 3;
    const int r0 = t >> 2;  // 0..63
#pragma unroll
    for (int it = 0; it < 4; ++it) {
      const int task = it * 64 + r0;
      if (task < 2 * NRH) {
        const int mat = task >= NRH;
        const int row = task - mat * NRH;
        const int hr = row / HALO_W;
        const int hc = row - hr * HALO_W;
        const int g = (hs + hr) * WW + (ws + hc);
        const uint4 val = *(const uint4*)(qkv + (size_t)g * 768 + 256 + mat * 256 +
                                          head * HD + lane4 * 8);
        ushort* dst = (mat ? Vs : Ks) + row * KROW + lane4 * 8;
        *(uint4*)dst = val;
      }
    }
  }
  __syncthreads();

  const int p = t >> 4;    // pixel 0..15
  const int tp = t & 15;   // lane within pixel
  const int i = i0 + (p >> 3), j = j0 + (p & 7);
  const int si = min(max(i - 3, 0), HH - KW);
  const int sj = min(max(j - 3, 0), WW - KW);
  const int lr0 = si - hs, lc0 = sj - ws;
  const int bi0 = si - i + (KW - 1);
  const int bj0 = sj - j + (KW - 1);

  // unpack q once, scale folded in
  float qf[32];
  {
    const ushort* qp = qkv + (size_t)(i * WW + j) * 768 + head * HD;
    const float scale = 0.17677669529663687f;  // 1/sqrt(32)
#pragma unroll
    for (int z = 0; z < 4; ++z) {
      const uint4 u = *(const uint4*)(qp + z * 8);
      qf[z * 8 + 0] = bflo(u.x) * scale;
      qf[z * 8 + 1] = bfhi(u.x) * scale;
      qf[z * 8 + 2] = bflo(u.y) * scale;
      qf[z * 8 + 3] = bfhi(u.y) * scale;
      qf[z * 8 + 4] = bflo(u.z) * scale;
      qf[z * 8 + 5] = bfhi(u.z) * scale;
      qf[z * 8 + 6] = bflo(u.w) * scale;
      qf[z * 8 + 7] = bfhi(u.w) * scale;
    }
  }

  // QK: each lane owns 4 of 49 neighbors
  const int nbeg = tp * 4;
  float lg[4];
#pragma unroll
  for (int z = 0; z < 4; ++z) lg[z] = -INFINITY;

#pragma unroll
  for (int z = 0; z < 4; ++z) {
    const int n = nbeg + z;
    if (n < KW * KW) {
      const int a = n / KW;
      const int c = n - a * KW;
      const int krow = (lr0 + a) * HALO_W + (lc0 + c);
      const ushort* kp = Ks + krow * KROW;
      float s = 0.f;
#pragma unroll
      for (int zz = 0; zz < 4; ++zz) {
        const uint4 k4 = *(const uint4*)(kp + zz * 8);
        s = fmaf(qf[zz * 8 + 0], bflo(k4.x), s);
        s = fmaf(qf[zz * 8 + 1], bfhi(k4.x), s);
        s = fmaf(qf[zz * 8 + 2], bflo(k4.y), s);
        s = fmaf(qf[zz * 8 + 3], bfhi(k4.y), s);
        s = fmaf(qf[zz * 8 + 4], bflo(k4.z), s);
        s = fmaf(qf[zz * 8 + 5], bfhi(k4.z), s);
        s = fmaf(qf[zz * 8 + 6], bflo(k4.w), s);
        s = fmaf(qf[zz * 8 + 7], bfhi(k4.w), s);
      }
      lg[z] = s + Rs[(bi0 + a) * 13 + (bj0 + c)];
    }
  }

  float m = fmaxf(fmaxf(lg[0], lg[1]), fmaxf(lg[2], lg[3]));
  m = fmaxf(m, __shfl_xor(m, 1, 16));
  m = fmaxf(m, __shfl_xor(m, 2, 16));
  m = fmaxf(m, __shfl_xor(m, 4, 16));
  m = fmaxf(m, __shfl_xor(m, 8, 16));

  float ssum = 0.f;
#pragma unroll
  for (int z = 0; z < 4; ++z) {
    const float e = __expf(lg[z] - m);  // exp(-inf)=0 for padding
    lg[z] = e;
    ssum += e;
  }
  ssum += __shfl_xor(ssum, 1, 16);
  ssum += __shfl_xor(ssum, 2, 16);
  ssum += __shfl_xor(ssum, 4, 16);
  ssum += __shfl_xor(ssum, 8, 16);
  const float inv = 1.f / ssum;

#pragma unroll
  for (int z = 0; z < 4; ++z) {
    const int n = nbeg + z;
    if (n < KW * KW) Ps[p][n] = lg[z] * inv;
  }
  __syncthreads();

  // PV: 4 neighbor-quarters x 4 dim-groups; lane = quarter*4 + dgroup
  const int quarter = tp >> 2;
  const int d0 = (tp & 3) * 8;
  float o[8] = {0.f, 0.f, 0.f, 0.f, 0.f, 0.f, 0.f, 0.f};
#pragma unroll
  for (int z = 0; z < 13; ++z) {
    const int n = quarter * 13 + z;
    if (n < KW * KW) {
      const int a = n / KW;
      const int c = n - a * KW;
      const float pr = Ps[p][n];
      const int vrow = (lr0 + a) * HALO_W + (lc0 + c);
      const uint4 v4 = *(const uint4*)(Vs + vrow * KROW + d0);
      o[0] = fmaf(pr, bflo(v4.x), o[0]);
      o[1] = fmaf(pr, bfhi(v4.x), o[1]);
      o[2] = fmaf(pr, bflo(v4.y), o[2]);
      o[3] = fmaf(pr, bfhi(v4.y), o[3]);
      o[4] = fmaf(pr, bflo(v4.z), o[4]);
      o[5] = fmaf(pr, bfhi(v4.z), o[5]);
      o[6] = fmaf(pr, bflo(v4.w), o[6]);
      o[7] = fmaf(pr, bfhi(v4.w), o[7]);
    }
  }
  // combine the four neighbor-quarters (lanes tp, tp^4, tp^8, tp^12)
#pragma unroll
  for (int z = 0; z < 8; ++z) {
    o[z] += __shfl_xor(o[z], 4, 16);
    o[z] += __shfl_xor(o[z], 8, 16);
  }

  if (quarter == 0) {
    uint4 st;
    st.x = pk2(o[0], o[1]);
    st.y = pk2(o[2], o[3]);
    st.z = pk2(o[4], o[5]);
    st.w = pk2(o[6], o[7]);
    *(uint4*)(aout + (size_t)(i * WW + j) * CC + head * HD + d0) = st;
  }
}

extern "C" void kernel_launch(void* const* d_in, const int* in_sizes, int n_in,
                              void* d_out, int out_size, void* d_ws, size_t ws_size,
                              hipStream_t stream) {
  const float* x      = (const float*)d_in[0];
  const float* qkv_w  = (const float*)d_in[1];
  const float* qkv_b  = (const float*)d_in[2];
  const float* proj_w = (const float*)d_in[3];
  const float* proj_b = (const float*)d_in[4];
  const float* rpb    = (const float*)d_in[5];
  float* out = (float*)d_out;

  // workspace (ushort elements)
  ushort* qkvb  = (ushort*)d_ws;            // [4096,768] bf16
  ushort* aoutb = qkvb + 3145728;           // [4096,256] bf16

  // 1) QKV projection (x f32 converted in staging) -> bf16 qkv
  gemm4<768, false, true><<<dim3(64, 12), 256, 0, stream>>>(
      x, qkv_w, qkv_b, qkvb);

  // 2) neighborhood attention -> bf16 [4096,256]
  natten5<<<dim3(256, NHEAD), 256, 0, stream>>>(qkvb, rpb, aoutb);

  // 3) output projection (A bf16, proj_w converted in staging) -> f32 out
  gemm4<256, true, false><<<dim3(64, 4), 256, 0, stream>>>(
      aoutb, proj_w, proj_b, out);
}